// Round 4
// baseline (22799.007 us; speedup 1.0000x reference)
//
#include <hip/hip_runtime.h>
#include <hip/hip_fp16.h>

#define T_STEPS 2048
#define B_SZ 128
#define I_SZ 10
#define H_SZ 512

#define BSPLIT 4
#define HSPLIT 32
#define NWG (BSPLIT * HSPLIT)   // 128 workgroups
#define BTILE (B_SZ / BSPLIT)   // 32 batch rows per wg
#define HTILE (H_SZ / HSPLIT)   // 16 hidden cols per wg
#define HBUF_Q ((B_SZ * H_SZ) / 2)   // 32768 u64 per buffer

typedef _Float16 f16x8 __attribute__((ext_vector_type(8)));
typedef float f32x4 __attribute__((ext_vector_type(4)));
typedef float f32x2 __attribute__((ext_vector_type(2)));
typedef unsigned long long u64t;

// Zero both tagged h buffers (tags live in hi dwords). Must run before every
// persistent launch: leftover tags from a previous replay (or 0xAA poison,
// which reads as tag 0xAAAAAAAA >= any target) would satisfy the tag check.
__global__ void clear_hbuf_kernel(u64t* p) {
    const int i = blockIdx.x * blockDim.x + threadIdx.x;   // 16384 threads
    #pragma unroll
    for (int k = 0; k < 4; ++k)
        __hip_atomic_store(p + i + k * 16384, 0ull,
                           __ATOMIC_RELAXED, __HIP_MEMORY_SCOPE_AGENT);
}

// Persistent LSTM, tagged-payload sync:
//   h element pair (2 x fp16) + step tag packed in ONE u64, stored with a
//   single agent-scope relaxed atomic (sc0/sc1, lands at the coherent LLC).
//   The data store IS the flag: no producer-side waitcnt, no flag array,
//   no end-of-step barrier. Consumers prefetch all 16 k-chunks and verify
//   4 tags per chunk (__all), retrying only stale chunks.
// Invariant making the double buffer safe: storing tag t+2 requires having
//   consumed all of tag t+1, which requires every wg published t+1, which
//   requires every wg fully consumed tag t -> nobody still reads the buffer
//   being overwritten.
__global__ __launch_bounds__(256, 1) void lstm_persistent(
    const float* __restrict__ x,     // [T,B,I]
    const float* __restrict__ hx,    // [B,H]
    const float* __restrict__ cx,    // [B,H]
    const float* __restrict__ W_ih,  // [4H,I]
    const float* __restrict__ W_hh,  // [4H,H]
    const float* __restrict__ b_ih,  // [4H]
    const float* __restrict__ b_hh,  // [4H]
    float* __restrict__ out,         // [3*B*H] = h, h, c
    u64t* hbuf)                      // [2][B][H/2] tagged pairs
{
    __shared__ float lds_g[2][4][BTILE][HTILE + 1];   // double-buffered, padded

    const int wg   = blockIdx.x;
    const int bs   = wg >> 5;          // batch split (0..3)
    const int hs   = wg & 31;          // hidden split (0..31)
    const int tid  = threadIdx.x;
    const int wid  = tid >> 6;         // wave 0..3
    const int lane = tid & 63;
    const int m    = wid & 1;          // m-fragment (16 batch rows)
    const int gp   = wid >> 1;         // gate pair: 0 -> {i,f}, 1 -> {g,o}

    const int fr_col = lane & 15;
    const int fr_kg  = lane >> 4;      // 0..3

    const int a_row = bs * BTILE + m * 16 + fr_col;   // global batch row for A

    const int gate0 = 2 * gp;          // 0 (i) / 2 (g)
    const int gate1 = 2 * gp + 1;      // 1 (f) / 3 (o)
    const int hc_g  = hs * HTILE + fr_col;
    const int gc0   = gate0 * H_SZ + hc_g;
    const int gc1   = gate1 * H_SZ + hc_g;

    // ---- W_hh fragments (B operand), fp16, register-resident
    f16x8 wf0[16], wf1[16];
    #pragma unroll
    for (int kk = 0; kk < 16; ++kk) {
        const int k0 = kk * 32 + fr_kg * 8;
        const float* p0 = W_hh + (size_t)gc0 * H_SZ + k0;
        const float* p1 = W_hh + (size_t)gc1 * H_SZ + k0;
        f16x8 w0, w1;
        #pragma unroll
        for (int e = 0; e < 8; ++e) {
            w0[e] = (_Float16)p0[e];
            w1[e] = (_Float16)p1[e];
        }
        wf0[kk] = w0;
        wf1[kk] = w1;
    }

    // ---- W_ih rows + combined bias
    float wih0[I_SZ], wih1[I_SZ];
    #pragma unroll
    for (int i = 0; i < I_SZ; ++i) {
        wih0[i] = W_ih[gc0 * I_SZ + i];
        wih1[i] = W_ih[gc1 * I_SZ + i];
    }
    const float bias0 = b_ih[gc0] + b_hh[gc0];
    const float bias1 = b_ih[gc1] + b_hh[gc1];

    // ---- persistent state: 2 adjacent cells per thread
    const int v0   = tid * 2;
    const int cb0  = v0 >> 4, chc0 = v0 & 15;       // chc0 even
    const int gb0  = bs * BTILE + cb0;
    const int ghc0 = hs * HTILE + chc0;
    const size_t my_q = (size_t)gb0 * (H_SZ / 2) + (ghc0 >> 1);  // u64 index

    float c0 = cx[gb0 * H_SZ + ghc0];
    float c1 = cx[gb0 * H_SZ + ghc0 + 1];
    float h0 = hx[gb0 * H_SZ + ghc0];
    float h1 = hx[gb0 * H_SZ + ghc0 + 1];

    // ---- publish initial h with tag 1 into buffer 0 (fire-and-forget)
    {
        union { _Float16 hp[2]; unsigned u; } pk;
        pk.hp[0] = (_Float16)h0; pk.hp[1] = (_Float16)h1;
        const u64t v = ((u64t)1u << 32) | pk.u;
        __hip_atomic_store(hbuf + my_q, v, __ATOMIC_RELAXED, __HIP_MEMORY_SCOPE_AGENT);
    }

    #pragma unroll 1
    for (int t = 0; t < T_STEPS; ++t) {
        // -- prefetch ALL 16 tagged h-chunks for this step (pipelined sc1 loads)
        const u64t* hb = hbuf + (size_t)(t & 1) * HBUF_Q;
        const u64t* ap = hb + (size_t)a_row * (H_SZ / 2) + fr_kg * 4;
        u64t q[16][4];
        #pragma unroll
        for (int kk = 0; kk < 16; ++kk) {
            #pragma unroll
            for (int j = 0; j < 4; ++j)
                q[kk][j] = __hip_atomic_load(ap + kk * 16 + j,
                                             __ATOMIC_RELAXED, __HIP_MEMORY_SCOPE_AGENT);
        }

        // -- x_t @ W_ih^T + bias on VALU (L2-cached direct loads, no LDS)
        f32x4 acc0, acc1;
        #pragma unroll
        for (int r = 0; r < 4; ++r) {
            const int bl = m * 16 + fr_kg * 4 + r;
            const f32x2* xp = (const f32x2*)(x + ((size_t)t * B_SZ + bs * BTILE + bl) * I_SZ);
            const f32x2 a0 = xp[0], a1 = xp[1], a2 = xp[2], a3 = xp[3], a4 = xp[4];
            float s0 = bias0, s1 = bias1;
            s0 += a0.x * wih0[0] + a0.y * wih0[1] + a1.x * wih0[2] + a1.y * wih0[3]
                + a2.x * wih0[4] + a2.y * wih0[5] + a3.x * wih0[6] + a3.y * wih0[7]
                + a4.x * wih0[8] + a4.y * wih0[9];
            s1 += a0.x * wih1[0] + a0.y * wih1[1] + a1.x * wih1[2] + a1.y * wih1[3]
                + a2.x * wih1[4] + a2.y * wih1[5] + a3.x * wih1[6] + a3.y * wih1[7]
                + a4.x * wih1[8] + a4.y * wih1[9];
            acc0[r] = s0;
            acc1[r] = s1;
        }
        f32x4 acc0o = {0.f, 0.f, 0.f, 0.f}, acc1o = {0.f, 0.f, 0.f, 0.f};

        // -- per-chunk: verify tags (retry if stale), then 2 MFMAs
        const unsigned tgt = (unsigned)(t + 1);
        #pragma unroll
        for (int kk = 0; kk < 16; ++kk) {
            while (!__all((unsigned)(q[kk][0] >> 32) >= tgt &&
                          (unsigned)(q[kk][1] >> 32) >= tgt &&
                          (unsigned)(q[kk][2] >> 32) >= tgt &&
                          (unsigned)(q[kk][3] >> 32) >= tgt)) {
                __builtin_amdgcn_s_sleep(1);
                #pragma unroll
                for (int j = 0; j < 4; ++j)
                    q[kk][j] = __hip_atomic_load(ap + kk * 16 + j,
                                                 __ATOMIC_RELAXED, __HIP_MEMORY_SCOPE_AGENT);
            }
            union { unsigned w[4]; f16x8 v; } au;
            #pragma unroll
            for (int j = 0; j < 4; ++j) au.w[j] = (unsigned)q[kk][j];
            if (kk & 1) {
                acc0o = __builtin_amdgcn_mfma_f32_16x16x32_f16(au.v, wf0[kk], acc0o, 0, 0, 0);
                acc1o = __builtin_amdgcn_mfma_f32_16x16x32_f16(au.v, wf1[kk], acc1o, 0, 0, 0);
            } else {
                acc0 = __builtin_amdgcn_mfma_f32_16x16x32_f16(au.v, wf0[kk], acc0, 0, 0, 0);
                acc1 = __builtin_amdgcn_mfma_f32_16x16x32_f16(au.v, wf1[kk], acc1, 0, 0, 0);
            }
        }
        acc0 += acc0o;
        acc1 += acc1o;

        // -- nonlinearities, exchange through (double-buffered) LDS
        #pragma unroll
        for (int r = 0; r < 4; ++r) {
            const int bl = m * 16 + fr_kg * 4 + r;
            const float p0 = acc0[r], p1 = acc1[r];
            float n0, n1;
            if (gp == 0) {          // i, f: sigmoid
                n0 = 1.f / (1.f + __expf(-p0));
                n1 = 1.f / (1.f + __expf(-p1));
            } else {                // g: tanh, o: sigmoid
                const float e = __expf(-2.f * p0);
                n0 = (1.f - e) / (1.f + e);
                n1 = 1.f / (1.f + __expf(-p1));
            }
            lds_g[t & 1][gate0][bl][fr_col] = n0;
            lds_g[t & 1][gate1][bl][fr_col] = n1;
        }
        __syncthreads();   // the ONLY barrier per step

        // -- c/h update for owned cells; publish tagged h for step t+1
        {
            const float ig0 = lds_g[t & 1][0][cb0][chc0],     fg0 = lds_g[t & 1][1][cb0][chc0];
            const float gg0 = lds_g[t & 1][2][cb0][chc0],     og0 = lds_g[t & 1][3][cb0][chc0];
            const float ig1 = lds_g[t & 1][0][cb0][chc0 + 1], fg1 = lds_g[t & 1][1][cb0][chc0 + 1];
            const float gg1 = lds_g[t & 1][2][cb0][chc0 + 1], og1 = lds_g[t & 1][3][cb0][chc0 + 1];
            c0 = fg0 * c0 + ig0 * gg0;
            c1 = fg1 * c1 + ig1 * gg1;
            const float e0 = __expf(-2.f * c0), e1 = __expf(-2.f * c1);
            h0 = og0 * (1.f - e0) / (1.f + e0);
            h1 = og1 * (1.f - e1) / (1.f + e1);
            if (t < T_STEPS - 1) {
                union { _Float16 hp[2]; unsigned u; } pk;
                pk.hp[0] = (_Float16)h0; pk.hp[1] = (_Float16)h1;
                const u64t v = ((u64t)(unsigned)(t + 2) << 32) | pk.u;
                u64t* hbn = hbuf + (size_t)((t + 1) & 1) * HBUF_Q;
                __hip_atomic_store(hbn + my_q, v, __ATOMIC_RELAXED, __HIP_MEMORY_SCOPE_AGENT);
            }
        }
    }

    // ---- outputs: (h, h, c), each [B,H] f32
    out[gb0 * H_SZ + ghc0]                       = h0;
    out[gb0 * H_SZ + ghc0 + 1]                   = h1;
    out[B_SZ * H_SZ + gb0 * H_SZ + ghc0]         = h0;
    out[B_SZ * H_SZ + gb0 * H_SZ + ghc0 + 1]     = h1;
    out[2 * B_SZ * H_SZ + gb0 * H_SZ + ghc0]     = c0;
    out[2 * B_SZ * H_SZ + gb0 * H_SZ + ghc0 + 1] = c1;
}

extern "C" void kernel_launch(void* const* d_in, const int* in_sizes, int n_in,
                              void* d_out, int out_size, void* d_ws, size_t ws_size,
                              hipStream_t stream) {
    const float* x    = (const float*)d_in[0];
    const float* hx   = (const float*)d_in[1];
    const float* cx   = (const float*)d_in[2];
    const float* W_ih = (const float*)d_in[3];
    const float* W_hh = (const float*)d_in[4];
    const float* b_ih = (const float*)d_in[5];
    const float* b_hh = (const float*)d_in[6];
    float* out = (float*)d_out;

    // workspace: [0, 512KB) tagged h double-buffer (2 x 32768 u64)
    u64t* hbuf = (u64t*)d_ws;

    clear_hbuf_kernel<<<64, 256, 0, stream>>>(hbuf);
    lstm_persistent<<<NWG, 256, 0, stream>>>(x, hx, cx, W_ih, W_hh, b_ih, b_hh,
                                             out, hbuf);
}

// Round 5
// 16826.147 us; speedup vs baseline: 1.3550x; 1.3550x over previous
//
#include <hip/hip_runtime.h>
#include <hip/hip_fp16.h>

#define T_STEPS 2048
#define B_SZ 128
#define I_SZ 10
#define H_SZ 512

#define BSPLIT 4
#define HSPLIT 32
#define NWG (BSPLIT * HSPLIT)   // 128 workgroups
#define BTILE (B_SZ / BSPLIT)   // 32 batch rows per wg
#define HTILE (H_SZ / HSPLIT)   // 16 hidden cols per wg
#define HBUF_Q ((B_SZ * H_SZ) / 2)   // 32768 tagged u64 per buffer

typedef _Float16 f16x8 __attribute__((ext_vector_type(8)));
typedef float f32x4 __attribute__((ext_vector_type(4)));
typedef float f32x2 __attribute__((ext_vector_type(2)));
typedef unsigned long long u64t;

// Zero both tagged h buffers. Must run before every persistent launch:
// leftover tags from a previous replay (or 0xAA poison = tag 0xAAAAAAAA)
// would satisfy the tag check.
__global__ void clear_hbuf_kernel(u64t* p) {
    const int i = blockIdx.x * blockDim.x + threadIdx.x;   // 16384 threads
    #pragma unroll
    for (int k = 0; k < 4; ++k)
        __hip_atomic_store(p + i + k * 16384, 0ull,
                           __ATOMIC_RELAXED, __HIP_MEMORY_SCOPE_AGENT);
}

// Persistent LSTM, tagged-payload sync, converged bulk poll, K-split waves.
//
//   h pair (2 x fp16) + step tag in ONE u64, agent-scope relaxed store:
//   fire-and-forget — the data store IS the flag. Consumer wave (m,gp)
//   computes ALL 4 gates for rows [m*16,m*16+16) over K-half gp: it issues
//   its whole 32-u64 tagged sweep pipelined, checks all tags with one
//   __all, and retries the whole sweep — detection latency is ONE load
//   latency, not 16 serialized chunk-retries (the R4 mistake).
//
//   Partial (half-K) gate pre-activations combine through LDS (raw f32,
//   double-buffered by t&1); each thread then sums halves, applies
//   nonlinearities for its 2 owned cells, and publishes tagged h.
//   One __syncthreads per step. Cross-step LDS WAR is protected by the
//   poll: passing the t+1 poll requires every producer stored h(t+1),
//   which happens after their step-t LDS reads.
//
//   Double-buffer safety: storing tag t+2 requires having consumed t+1,
//   which requires all wgs published t+1, which requires all consumed t
//   -> nobody still reads the buffer being overwritten.
__global__ __launch_bounds__(256, 1) void lstm_persistent(
    const float* __restrict__ x,     // [T,B,I]
    const float* __restrict__ hx,    // [B,H]
    const float* __restrict__ cx,    // [B,H]
    const float* __restrict__ W_ih,  // [4H,I]
    const float* __restrict__ W_hh,  // [4H,H]
    const float* __restrict__ b_ih,  // [4H]
    const float* __restrict__ b_hh,  // [4H]
    float* __restrict__ out,         // [3*B*H] = h, h, c
    u64t* hbuf)                      // [2][B][H/2] tagged pairs
{
    // [buf][gp][gate][row][col]: raw half-K gate partials, f32
    __shared__ float lds_part[2][2][4][BTILE][HTILE + 1];   // ~34.8 KB

    const int wg   = blockIdx.x;
    const int bs   = wg >> 5;          // batch split (0..3)
    const int hs   = wg & 31;          // hidden split (0..31)
    const int tid  = threadIdx.x;
    const int wid  = tid >> 6;         // wave 0..3
    const int lane = tid & 63;
    const int m    = wid & 1;          // row-half: rows m*16..m*16+15
    const int gp   = wid >> 1;         // K-half:  chunks gp*8..gp*8+7

    const int fr_col = lane & 15;
    const int fr_kg  = lane >> 4;      // 0..3

    const int a_row = bs * BTILE + m * 16 + fr_col;   // global batch row (A operand)

    const int hc_g  = hs * HTILE + fr_col;            // W_hh column base
    // this wave's x-projection gates (split across gp to balance):
    const int gate0 = 2 * gp;
    const int gate1 = 2 * gp + 1;

    // ---- W_hh B-fragments: ALL 4 gates x our 8 K-chunks, fp16 registers
    f16x8 wf[4][8];
    #pragma unroll
    for (int g = 0; g < 4; ++g) {
        #pragma unroll
        for (int c = 0; c < 8; ++c) {
            const int k0 = (gp * 8 + c) * 32 + fr_kg * 8;
            const float* p = W_hh + (size_t)(g * H_SZ + hc_g) * H_SZ + k0;
            f16x8 w;
            #pragma unroll
            for (int e = 0; e < 8; ++e) w[e] = (_Float16)p[e];
            wf[g][c] = w;
        }
    }

    // ---- W_ih rows + combined bias for our 2 x-proj gates
    float wih0[I_SZ], wih1[I_SZ];
    #pragma unroll
    for (int i = 0; i < I_SZ; ++i) {
        wih0[i] = W_ih[(gate0 * H_SZ + hc_g) * I_SZ + i];
        wih1[i] = W_ih[(gate1 * H_SZ + hc_g) * I_SZ + i];
    }
    const float bias0 = b_ih[gate0 * H_SZ + hc_g] + b_hh[gate0 * H_SZ + hc_g];
    const float bias1 = b_ih[gate1 * H_SZ + hc_g] + b_hh[gate1 * H_SZ + hc_g];

    // ---- persistent state: 2 adjacent cells per thread
    const int v0   = tid * 2;
    const int cb0  = v0 >> 4, chc0 = v0 & 15;       // chc0 even
    const int gb0  = bs * BTILE + cb0;
    const int ghc0 = hs * HTILE + chc0;
    const size_t my_q = (size_t)gb0 * (H_SZ / 2) + (ghc0 >> 1);

    float c0 = cx[gb0 * H_SZ + ghc0];
    float c1 = cx[gb0 * H_SZ + ghc0 + 1];
    float h0 = hx[gb0 * H_SZ + ghc0];
    float h1 = hx[gb0 * H_SZ + ghc0 + 1];

    // ---- publish initial h with tag 1 into buffer 0 (fire-and-forget)
    {
        union { _Float16 hp[2]; unsigned u; } pk;
        pk.hp[0] = (_Float16)h0; pk.hp[1] = (_Float16)h1;
        const u64t v = ((u64t)1u << 32) | pk.u;
        __hip_atomic_store(hbuf + my_q, v, __ATOMIC_RELAXED, __HIP_MEMORY_SCOPE_AGENT);
    }

    #pragma unroll 1
    for (int t = 0; t < T_STEPS; ++t) {
        // -- x_t @ W_ih^T + bias for our 2 gates (pre-poll, off critical path)
        f32x4 acc[4];
        #pragma unroll
        for (int g = 0; g < 4; ++g) acc[g] = (f32x4){0.f, 0.f, 0.f, 0.f};
        #pragma unroll
        for (int r = 0; r < 4; ++r) {
            const int grow = bs * BTILE + m * 16 + fr_kg * 4 + r;
            const f32x2* xp = (const f32x2*)(x + ((size_t)t * B_SZ + grow) * I_SZ);
            const f32x2 a0 = xp[0], a1 = xp[1], a2 = xp[2], a3 = xp[3], a4 = xp[4];
            float s0 = bias0, s1 = bias1;
            s0 += a0.x * wih0[0] + a0.y * wih0[1] + a1.x * wih0[2] + a1.y * wih0[3]
                + a2.x * wih0[4] + a2.y * wih0[5] + a3.x * wih0[6] + a3.y * wih0[7]
                + a4.x * wih0[8] + a4.y * wih0[9];
            s1 += a0.x * wih1[0] + a0.y * wih1[1] + a1.x * wih1[2] + a1.y * wih1[3]
                + a2.x * wih1[4] + a2.y * wih1[5] + a3.x * wih1[6] + a3.y * wih1[7]
                + a4.x * wih1[8] + a4.y * wih1[9];
            acc[gate0][r] = s0;
            acc[gate1][r] = s1;
        }

        // -- converged bulk poll: issue ALL 32 tagged u64 loads (pipelined),
        //    verify ALL tags with one __all; on failure re-sweep.
        const u64t* hb = hbuf + (size_t)(t & 1) * HBUF_Q;
        const u64t* ap = hb + (size_t)a_row * (H_SZ / 2) + gp * 128 + fr_kg * 4;
        const unsigned tgt = (unsigned)(t + 1);
        u64t q[8][4];
        #pragma unroll
        for (int c = 0; c < 8; ++c)
            #pragma unroll
            for (int j = 0; j < 4; ++j)
                q[c][j] = __hip_atomic_load(ap + c * 16 + j,
                                            __ATOMIC_RELAXED, __HIP_MEMORY_SCOPE_AGENT);
        for (;;) {
            unsigned ok = 1u;
            #pragma unroll
            for (int c = 0; c < 8; ++c)
                #pragma unroll
                for (int j = 0; j < 4; ++j)
                    ok &= (unsigned)((unsigned)(q[c][j] >> 32) >= tgt);
            if (__all(ok)) break;
            __builtin_amdgcn_s_sleep(1);
            #pragma unroll
            for (int c = 0; c < 8; ++c)
                #pragma unroll
                for (int j = 0; j < 4; ++j)
                    q[c][j] = __hip_atomic_load(ap + c * 16 + j,
                                                __ATOMIC_RELAXED, __HIP_MEMORY_SCOPE_AGENT);
        }

        // -- MFMA: 8 K-chunks x 4 gates (4 independent acc chains)
        #pragma unroll
        for (int c = 0; c < 8; ++c) {
            union { unsigned w[4]; f16x8 v; } au;
            #pragma unroll
            for (int j = 0; j < 4; ++j) au.w[j] = (unsigned)q[c][j];
            #pragma unroll
            for (int g = 0; g < 4; ++g)
                acc[g] = __builtin_amdgcn_mfma_f32_16x16x32_f16(au.v, wf[g][c], acc[g], 0, 0, 0);
        }

        // -- write raw half-K partials to LDS (double-buffered by t&1)
        #pragma unroll
        for (int g = 0; g < 4; ++g)
            #pragma unroll
            for (int r = 0; r < 4; ++r)
                lds_part[t & 1][gp][g][m * 16 + fr_kg * 4 + r][fr_col] = acc[g][r];
        __syncthreads();   // the ONLY barrier per step

        // -- sum K-halves, nonlinearities, c/h update, publish tagged h(t+1)
        {
            const int b = t & 1;
            const float i0 = lds_part[b][0][0][cb0][chc0]     + lds_part[b][1][0][cb0][chc0];
            const float f0 = lds_part[b][0][1][cb0][chc0]     + lds_part[b][1][1][cb0][chc0];
            const float g0 = lds_part[b][0][2][cb0][chc0]     + lds_part[b][1][2][cb0][chc0];
            const float o0 = lds_part[b][0][3][cb0][chc0]     + lds_part[b][1][3][cb0][chc0];
            const float i1 = lds_part[b][0][0][cb0][chc0 + 1] + lds_part[b][1][0][cb0][chc0 + 1];
            const float f1 = lds_part[b][0][1][cb0][chc0 + 1] + lds_part[b][1][1][cb0][chc0 + 1];
            const float g1 = lds_part[b][0][2][cb0][chc0 + 1] + lds_part[b][1][2][cb0][chc0 + 1];
            const float o1 = lds_part[b][0][3][cb0][chc0 + 1] + lds_part[b][1][3][cb0][chc0 + 1];

            const float ig0 = 1.f / (1.f + __expf(-i0));
            const float fg0 = 1.f / (1.f + __expf(-f0));
            const float eg0 = __expf(-2.f * g0);
            const float gg0 = (1.f - eg0) / (1.f + eg0);
            const float og0 = 1.f / (1.f + __expf(-o0));
            const float ig1 = 1.f / (1.f + __expf(-i1));
            const float fg1 = 1.f / (1.f + __expf(-f1));
            const float eg1 = __expf(-2.f * g1);
            const float gg1 = (1.f - eg1) / (1.f + eg1);
            const float og1 = 1.f / (1.f + __expf(-o1));

            c0 = fg0 * c0 + ig0 * gg0;
            c1 = fg1 * c1 + ig1 * gg1;
            const float e0 = __expf(-2.f * c0), e1 = __expf(-2.f * c1);
            h0 = og0 * (1.f - e0) / (1.f + e0);
            h1 = og1 * (1.f - e1) / (1.f + e1);

            if (t < T_STEPS - 1) {
                union { _Float16 hp[2]; unsigned u; } pk;
                pk.hp[0] = (_Float16)h0; pk.hp[1] = (_Float16)h1;
                const u64t v = ((u64t)(unsigned)(t + 2) << 32) | pk.u;
                u64t* hbn = hbuf + (size_t)((t + 1) & 1) * HBUF_Q;
                __hip_atomic_store(hbn + my_q, v, __ATOMIC_RELAXED, __HIP_MEMORY_SCOPE_AGENT);
            }
        }
    }

    // ---- outputs: (h, h, c), each [B,H] f32
    out[gb0 * H_SZ + ghc0]                       = h0;
    out[gb0 * H_SZ + ghc0 + 1]                   = h1;
    out[B_SZ * H_SZ + gb0 * H_SZ + ghc0]         = h0;
    out[B_SZ * H_SZ + gb0 * H_SZ + ghc0 + 1]     = h1;
    out[2 * B_SZ * H_SZ + gb0 * H_SZ + ghc0]     = c0;
    out[2 * B_SZ * H_SZ + gb0 * H_SZ + ghc0 + 1] = c1;
}

extern "C" void kernel_launch(void* const* d_in, const int* in_sizes, int n_in,
                              void* d_out, int out_size, void* d_ws, size_t ws_size,
                              hipStream_t stream) {
    const float* x    = (const float*)d_in[0];
    const float* hx   = (const float*)d_in[1];
    const float* cx   = (const float*)d_in[2];
    const float* W_ih = (const float*)d_in[3];
    const float* W_hh = (const float*)d_in[4];
    const float* b_ih = (const float*)d_in[5];
    const float* b_hh = (const float*)d_in[6];
    float* out = (float*)d_out;

    // workspace: [0, 512KB) tagged h double-buffer (2 x 32768 u64)
    u64t* hbuf = (u64t*)d_ws;

    clear_hbuf_kernel<<<64, 256, 0, stream>>>(hbuf);
    lstm_persistent<<<NWG, 256, 0, stream>>>(x, hx, cx, W_ih, W_hh, b_ih, b_hh,
                                             out, hbuf);
}